// Round 11
// baseline (262.370 us; speedup 1.0000x reference)
//
#include <hip/hip_runtime.h>

#define N_NODES 100000
#define N_EDGES 3200000
#define IN_DIM  29
#define HID_DIM 64
#define NBUCK   391            // coarse buckets of 256 dst nodes
#define CNODES  256
#define CAP     10240          // slots/coarse bucket; mean 8189, +22 sigma
#define SUB     8              // consumer sub-buckets per coarse bucket
#define SNODES  32             // dst nodes per sub-bucket
#define CAP_S   1408           // LDS stage slots; mean 1024, sigma 32 -> +12 sigma
#define EPT     8
#define EPB     4096           // 512 threads * 8 edges

// ---- ws layout (4-byte units) ---------------------------------------------
#define OFF_CUR   0            // gcursor[NBUCK] (bucket sizes; region b at b*CAP)
#define OFF_DEGC  512          // degc[N]
#define OFF_DINV  100512       // dinv[N]
#define OFF_ZS    200512       // zs[2N]
#define OFF_EBUF  400512       // ebuf[NBUCK*CAP] = 4,003,840 (unsorted, src|dl8<<17)
#define OFF_XS    4404352      // xs bf16[32N] = 16N uints (64B aligned)
// total ~6.0M words = 24 MB

typedef unsigned uv2 __attribute__((ext_vector_type(2)));

static __device__ __forceinline__ unsigned short f2bf(float f) {
    unsigned u = __float_as_uint(f);
    u += 0x7fffu + ((u >> 16) & 1u);   // RNE
    return (unsigned short)(u >> 16);
}

static __device__ __forceinline__ void unpack_add(float4& acc, uv2 a) {
    acc.x += __uint_as_float(a.x << 16);
    acc.y += __uint_as_float(a.x & 0xFFFF0000u);
    acc.z += __uint_as_float(a.y << 16);
    acc.w += __uint_as_float(a.y & 0xFFFF0000u);
}

// ---------------- partition: coarse-bucket edges by dst>>8 ------------------
__global__ __launch_bounds__(512) void partition_kernel(const int* __restrict__ ei,
        int* __restrict__ gcursor, int* __restrict__ ebuf) {
    __shared__ int lhist[NBUCK];
    __shared__ int lcur[NBUCK];
    int tid = threadIdx.x;
    for (int i = tid; i < NBUCK; i += 512) lhist[i] = 0;
    __syncthreads();

    int base = blockIdx.x * EPB + tid * EPT;     // 8-aligned; never straddles E
    int dv[EPT], sv[EPT];
    bool valid = (base < N_EDGES);
    if (valid) {
        const int4* dp = (const int4*)(ei + N_EDGES + base);
        const int4* sp = (const int4*)(ei + base);
        #pragma unroll
        for (int qq = 0; qq < 2; ++qq) {
            int4 t = dp[qq];
            dv[4*qq+0] = t.x; dv[4*qq+1] = t.y; dv[4*qq+2] = t.z; dv[4*qq+3] = t.w;
            int4 u = sp[qq];
            sv[4*qq+0] = u.x; sv[4*qq+1] = u.y; sv[4*qq+2] = u.z; sv[4*qq+3] = u.w;
        }
        #pragma unroll
        for (int j = 0; j < EPT; ++j) atomicAdd(&lhist[dv[j] >> 8], 1);
    }
    __syncthreads();
    for (int i = tid; i < NBUCK; i += 512) {
        int c = lhist[i];
        lcur[i] = c ? (atomicAdd(&gcursor[i], c) + i * CAP) : 0;  // claim base
    }
    __syncthreads();
    if (valid) {
        #pragma unroll
        for (int j = 0; j < EPT; ++j) {
            int d = dv[j];
            int pos = atomicAdd(&lcur[d >> 8], 1);     // LDS cursor
            ebuf[pos] = sv[j] | ((d & 255) << 17);     // src 17 bits, dl8 8 bits
        }
    }
}

// ---- per-coarse-bucket degree count -> degc/dinv, and xs = bf16(x*dinv) ----
__global__ __launch_bounds__(1024) void degcnt_kernel(const int* __restrict__ gcursor,
        const int* __restrict__ ebuf, const float* __restrict__ x,
        int* __restrict__ degc, float* __restrict__ dinv,
        unsigned int* __restrict__ xsb) {
    __shared__ int   cnt[CNODES];
    __shared__ float dls[CNODES];
    int b = blockIdx.x, tid = threadIdx.x;
    if (tid < CNODES) cnt[tid] = 0;
    __syncthreads();
    int base = b * CAP, sz = gcursor[b];
    for (int j = tid; j < sz; j += 1024)
        atomicAdd(&cnt[((unsigned)ebuf[base + j]) >> 17], 1);
    __syncthreads();
    if (tid < CNODES) {
        int node = b * CNODES + tid;
        if (node < N_NODES) {
            int c = cnt[tid];
            degc[node] = c;
            float dn = rsqrtf((float)c + 1.0f);        // +1 = self loop
            dinv[node] = dn;
            dls[tid] = dn;
        }
    }
    __syncthreads();
    for (int i = tid; i < CNODES * 16; i += 1024) {    // 2 features per uint
        int dl = i >> 4, kp = i & 15;
        int nd = b * CNODES + dl;
        if (nd < N_NODES) {
            float dn = dls[dl];
            int k0 = kp * 2, k1 = k0 + 1;
            float f0 = (k0 < IN_DIM) ? x[nd * IN_DIM + k0] * dn : 0.0f;
            float f1 = (k1 < IN_DIM) ? x[nd * IN_DIM + k1] * dn : 0.0f;
            xsb[(size_t)nd * 16 + kp] = (unsigned)f2bf(f0) | ((unsigned)f2bf(f1) << 16);
        }
    }
}

// --- sortfused: filter own eighth -> LDS sort -> gather + W1/relu/W2 --------
__global__ __launch_bounds__(256) void sortfused_kernel(const unsigned int* __restrict__ xs_,
        const int* __restrict__ gcursor, const int* __restrict__ ebuf,
        const int* __restrict__ degc, const float* __restrict__ dinv,
        const float* __restrict__ W1, const float* __restrict__ b1,
        const float* __restrict__ W2, float* __restrict__ zs) {
    __shared__ float w1s[IN_DIM * HID_DIM];            // 7.4 KB
    __shared__ float b1s[HID_DIM];
    __shared__ float w2s[HID_DIM * 2];
    __shared__ int   cnt_s[SNODES];
    __shared__ int   rs_s[SNODES];
    __shared__ int   cur_s[SNODES];
    __shared__ float dnv[SNODES];
    __shared__ int   stage[CAP_S];                     // 5.5 KB
    int tid = threadIdx.x;
    int b = blockIdx.x >> 3, q = blockIdx.x & 7;
    int nodeBase = b * CNODES + q * SNODES;
    for (int i = tid; i < IN_DIM * HID_DIM; i += 256) w1s[i] = W1[i];
    if (tid < HID_DIM) {
        b1s[tid] = b1[tid];
        w2s[tid * 2 + 0] = W2[tid * 2 + 0];
        w2s[tid * 2 + 1] = W2[tid * 2 + 1];
    }
    if (tid < SNODES) {                                // lanes 0..31 of wave 0
        int node = nodeBase + tid;
        int c  = (node < N_NODES) ? degc[node] : 0;
        dnv[tid] = (node < N_NODES) ? dinv[node] : 0.0f;
        cnt_s[tid] = c;
        int incl = c;                                  // shuffle inclusive scan
        #pragma unroll
        for (int off = 1; off < SNODES; off <<= 1) {
            int t = __shfl_up(incl, off);
            if (tid >= off) incl += t;
        }
        int excl = incl - c;
        rs_s[tid] = excl;
        cur_s[tid] = excl;
    }
    __syncthreads();

    int base = b * CAP, sz = gcursor[b];
    for (int j = tid; j < sz; j += 256) {              // stream + filter + place
        unsigned p = (unsigned)ebuf[base + j];
        int dl8 = (int)(p >> 17);
        if ((dl8 >> 5) == q) {
            int pos = atomicAdd(&cur_s[dl8 & 31], 1);
            stage[pos] = (int)(p & 0x1FFFF);
        }
    }
    __syncthreads();

    // gather + MLP: 4 waves x 8 nodes; 8 streams x 8 lanes; masked unroll-4
    int wave = tid >> 6, lane = tid & 63;
    int qs = lane >> 3, m = lane & 7;
    const uv2* xsbv = (const uv2*)xs_;                 // row = 8 uv2 (64 B)
    for (int i = 0; i < 8; ++i) {
        int dl = wave * 8 + i;
        int node = nodeBase + dl;
        if (node >= N_NODES) break;
        float4 acc = make_float4(0.f, 0.f, 0.f, 0.f);
        if (qs == 0)                                   // self loop in stream 0
            unpack_add(acc, xsbv[(size_t)node * 8 + m]);
        int rs = rs_s[dl], re = rs + cnt_s[dl];
        int last = re - 1;
        for (int j = rs + qs; j < re; j += 32) {       // 4 gathers in flight
            int j1 = j + 8, j2 = j + 16, j3 = j + 24;
            int s0 = stage[j];
            int s1 = stage[min(j1, last)];
            int s2 = stage[min(j2, last)];
            int s3 = stage[min(j3, last)];
            uv2 a0 = xsbv[(size_t)s0 * 8 + m];
            uv2 a1 = xsbv[(size_t)s1 * 8 + m];
            uv2 a2 = xsbv[(size_t)s2 * 8 + m];
            uv2 a3 = xsbv[(size_t)s3 * 8 + m];
            unpack_add(acc, a0);
            if (j1 < re) unpack_add(acc, a1);
            if (j2 < re) unpack_add(acc, a2);
            if (j3 < re) unpack_add(acc, a3);
        }
        #pragma unroll
        for (int msk = 8; msk <= 32; msk <<= 1) {      // fold 8 streams
            acc.x += __shfl_xor(acc.x, msk);
            acc.y += __shfl_xor(acc.y, msk);
            acc.z += __shfl_xor(acc.z, msk);
            acc.w += __shfl_xor(acc.w, msk);
        }
        float dn = dnv[dl];
        acc.x *= dn; acc.y *= dn; acc.z *= dn; acc.w *= dn;

        float h = b1s[lane];
        #pragma unroll
        for (int kk = 0; kk < IN_DIM; ++kk) {          // comp pick compile-time
            float comp = ((kk & 3) == 0) ? acc.x : ((kk & 3) == 1) ? acc.y
                       : ((kk & 3) == 2) ? acc.z : acc.w;
            h = fmaf(__shfl(comp, kk >> 2), w1s[kk * HID_DIM + lane], h);
        }
        h = fmaxf(h, 0.0f);

        float z0 = h * w2s[lane * 2 + 0];
        float z1 = h * w2s[lane * 2 + 1];
        #pragma unroll
        for (int off = 32; off > 0; off >>= 1) {
            z0 += __shfl_down(z0, off);
            z1 += __shfl_down(z1, off);
        }
        if (lane == 0) {                               // pre-scale by src dinv
            zs[node * 2 + 0] = z0 * dn;
            zs[node * 2 + 1] = z1 * dn;
        }
    }
}

// --- agg2: filter own eighth, gather zs (L2-resident), 2 LDS atomics/edge ---
__global__ __launch_bounds__(256) void agg2_kernel(const float* __restrict__ zs,
        const int* __restrict__ gcursor, const int* __restrict__ ebuf,
        const float* __restrict__ dinv, const float* __restrict__ b2,
        float* __restrict__ out) {
    __shared__ float aggz[SNODES * 2];
    int tid = threadIdx.x;
    int b = blockIdx.x >> 3, q = blockIdx.x & 7;
    int nodeBase = b * CNODES + q * SNODES;
    if (tid < SNODES * 2) {                            // seed with self term
        int node = nodeBase + (tid >> 1);
        aggz[tid] = (node < N_NODES) ? zs[node * 2 + (tid & 1)] : 0.0f;
    }
    __syncthreads();
    const float2* zs2 = (const float2*)zs;
    int base = b * CAP, sz = gcursor[b];
    int last = sz - 1;
    for (int j = tid; j < sz; j += 1024) {             // 4 stream reads in flight
        int j1 = j + 256, j2 = j + 512, j3 = j + 768;
        unsigned p0 = (unsigned)ebuf[base + j];
        unsigned p1 = (unsigned)ebuf[base + min(j1, last)];
        unsigned p2 = (unsigned)ebuf[base + min(j2, last)];
        unsigned p3 = (unsigned)ebuf[base + min(j3, last)];
        int d0 = (int)(p0 >> 17), d1 = (int)(p1 >> 17);
        int d2 = (int)(p2 >> 17), d3 = (int)(p3 >> 17);
        if ((d0 >> 5) == q) {
            float2 zv = zs2[p0 & 0x1FFFF];
            int o = (d0 & 31) * 2;
            atomicAdd(&aggz[o], zv.x); atomicAdd(&aggz[o + 1], zv.y);
        }
        if (j1 < sz && (d1 >> 5) == q) {
            float2 zv = zs2[p1 & 0x1FFFF];
            int o = (d1 & 31) * 2;
            atomicAdd(&aggz[o], zv.x); atomicAdd(&aggz[o + 1], zv.y);
        }
        if (j2 < sz && (d2 >> 5) == q) {
            float2 zv = zs2[p2 & 0x1FFFF];
            int o = (d2 & 31) * 2;
            atomicAdd(&aggz[o], zv.x); atomicAdd(&aggz[o + 1], zv.y);
        }
        if (j3 < sz && (d3 >> 5) == q) {
            float2 zv = zs2[p3 & 0x1FFFF];
            int o = (d3 & 31) * 2;
            atomicAdd(&aggz[o], zv.x); atomicAdd(&aggz[o + 1], zv.y);
        }
    }
    __syncthreads();
    if (tid < SNODES * 2) {
        int node = nodeBase + (tid >> 1);
        if (node < N_NODES) {
            int c = tid & 1;
            out[node * 2 + c] = dinv[node] * aggz[tid] + b2[c];
        }
    }
}

extern "C" void kernel_launch(void* const* d_in, const int* in_sizes, int n_in,
                              void* d_out, int out_size, void* d_ws, size_t ws_size,
                              hipStream_t stream) {
    const float* x  = (const float*)d_in[0];
    const int*   ei = (const int*)d_in[1];
    const float* W1 = (const float*)d_in[2];
    const float* b1 = (const float*)d_in[3];
    const float* W2 = (const float*)d_in[4];
    const float* b2 = (const float*)d_in[5];
    float* out = (float*)d_out;

    int*   wsi     = (int*)d_ws;
    float* wsf     = (float*)d_ws;
    int*   gcursor = wsi + OFF_CUR;
    int*   degc    = wsi + OFF_DEGC;
    float* dinv    = wsf + OFF_DINV;
    float* zs      = wsf + OFF_ZS;
    int*   ebuf    = wsi + OFF_EBUF;
    unsigned int* xsb = (unsigned int*)(wsi + OFF_XS);

    hipMemsetAsync(gcursor, 0, NBUCK * sizeof(int), stream);
    partition_kernel<<<(N_EDGES + EPB - 1) / EPB, 512, 0, stream>>>(ei, gcursor, ebuf);
    degcnt_kernel<<<NBUCK, 1024, 0, stream>>>(gcursor, ebuf, x, degc, dinv, xsb);
    sortfused_kernel<<<NBUCK * SUB, 256, 0, stream>>>(xsb, gcursor, ebuf, degc, dinv,
                                                      W1, b1, W2, zs);
    agg2_kernel<<<NBUCK * SUB, 256, 0, stream>>>(zs, gcursor, ebuf, dinv, b2, out);
}